// Round 9
// baseline (56.786 us; speedup 1.0000x reference)
//
#include <hip/hip_runtime.h>
#include <hip/hip_bf16.h>

#define T_TOTAL 200000

typedef float v4f __attribute__((ext_vector_type(4)));

// Parameter block layout (floats), phases in REVOLUTIONS, +0.25-shifted so
// sin(theta) = cos(2*pi*(fract(rev)-0.5)) (even poly, no sign fixup):
// [0..79]      layer0 quads per n<20 at 4n: {ww0', ph0'+0.25, C0=2cos(w*64d), A0}
// [80..1999]   layer1: per n<20, 96-float block at 80+96n:
//              [+m]=ww1'  [+32+m]=ph1'+0.25  [+64+m]=C1, m<32 (pads m>=25:
//              ww=0, ph=0.25 -> sin==0, C=2)
// [2000..4399] layer2: per n<25, 96-float block at 2000+96n (pads m>=30)
// [4400..4495] layer3: [+k]=ww3' [+32+k]=ph3'+0.25 [+64+k]=C3, k<32 (pads>=30)
// Prefetch overreads one block past layers 1/2; lands in the next layer's
// block (in-bounds, unused).
__device__ float g_P[4496];

// sin(2*pi*rev) via even poly: cos(2*pi*h), h = fract(rev)-0.5. |err| ~= 4e-5.
__device__ __forceinline__ float sinp(float rev) {
    float g = __builtin_amdgcn_fractf(rev);
    float h = g - 0.5f;
    float u = h * h;
    float p = fmaf(45.621248f, u, -82.391040f);
    p = fmaf(p, u, 64.671616f);
    p = fmaf(p, u, -19.730960f);
    p = fmaf(p, u, 0.9999618f);
    return p;
}

__global__ void prep_kernel(
    const float* __restrict__ A0,
    const float* __restrict__ w0, const float* __restrict__ phi0,
    const float* __restrict__ wc0, const float* __restrict__ phic0,
    const float* __restrict__ w1, const float* __restrict__ phi1,
    const float* __restrict__ wc1, const float* __restrict__ phic1,
    const float* __restrict__ w2, const float* __restrict__ phi2,
    const float* __restrict__ wc2, const float* __restrict__ phic2,
    const float* __restrict__ w3, const float* __restrict__ phi3,
    const float* __restrict__ wc3, const float* __restrict__ phic3)
{
    const int tid = blockIdx.x * blockDim.x + threadIdx.x;
    const int stride = blockDim.x * gridDim.x;

    const double I2PI = 0.15915494309189535;
    const double D64  = 64.0 * 999.0 / 199999.0;   // tv-step between j's

    const double ws0 = fmax((double)wc0[0], 0.0), ps0 = fmax((double)phic0[0], 0.0);
    const double ws1 = fmax((double)wc1[0], 0.0), ps1 = fmax((double)phic1[0], 0.0);
    const double ws2 = fmax((double)wc2[0], 0.0), ps2 = fmax((double)phic2[0], 0.0);
    const double ws3 = fmax((double)wc3[0], 0.0), ps3 = fmax((double)phic3[0], 0.0);

    for (int n = tid; n < 20; n += stride) {
        double wr = fmax((double)w0[n], 0.0) + ws0;
        g_P[4 * n]     = (float)(wr * I2PI);
        g_P[4 * n + 1] = (float)((fmax((double)phi0[n], 0.0) + ps0) * I2PI + 0.25);
        g_P[4 * n + 2] = (float)(2.0 * cos(wr * D64));
        g_P[4 * n + 3] = A0[n];
    }
    for (int k = tid; k < 20 * 32; k += stride) {
        const int n = k >> 5, m = k & 31;
        float wwf = 0.0f, phf = 0.25f, cf = 2.0f;
        if (m < 25) {
            const int s = m * 20 + n;
            double wr = fmax((double)w1[s], 0.0) + ws1;
            wwf = (float)(wr * I2PI);
            phf = (float)((fmax((double)phi1[s], 0.0) + ps1) * I2PI + 0.25);
            cf  = (float)(2.0 * cos(wr * D64));
        }
        g_P[80 + 96 * n + m]      = wwf;
        g_P[80 + 96 * n + 32 + m] = phf;
        g_P[80 + 96 * n + 64 + m] = cf;
    }
    for (int k = tid; k < 25 * 32; k += stride) {
        const int n = k >> 5, m = k & 31;
        float wwf = 0.0f, phf = 0.25f, cf = 2.0f;
        if (m < 30) {
            const int s = m * 25 + n;
            double wr = fmax((double)w2[s], 0.0) + ws2;
            wwf = (float)(wr * I2PI);
            phf = (float)((fmax((double)phi2[s], 0.0) + ps2) * I2PI + 0.25);
            cf  = (float)(2.0 * cos(wr * D64));
        }
        g_P[2000 + 96 * n + m]      = wwf;
        g_P[2000 + 96 * n + 32 + m] = phf;
        g_P[2000 + 96 * n + 64 + m] = cf;
    }
    for (int k = tid; k < 32; k += stride) {
        float wwf = 0.0f, phf = 0.25f, cf = 2.0f;
        if (k < 30) {
            double wr = fmax((double)w3[k], 0.0) + ws3;
            wwf = (float)(wr * I2PI);
            phf = (float)((fmax((double)phi3[k], 0.0) + ps3) * I2PI + 0.25);
            cf  = (float)(2.0 * cos(wr * D64));
        }
        g_P[4400 + k]      = wwf;
        g_P[4400 + 32 + k] = phf;
        g_P[4400 + 64 + k] = cf;
    }
}

// Block = 512 threads = 8 waves covering 256 t-values: t = tb + lane + 64*j,
// j=0..3 per thread. Per (m,n): j=0,1 direct poly, j=2,3 via 1-fma Chebyshev
// recurrence. Wave w owns m = 4w..4w+3. KEY CHANGE vs R8: all params are
// staged into LDS once per block, so every hot-loop load is a DS access --
// the DS lgkmcnt is IN-ORDER, so the 1-deep prefetch genuinely overlaps
// (SMEM is out-of-order: any wait drains to 0, which serialized R7/R8).
// All t-staged LDS uses scalar [row][j][lane] layout: strictly conflict-free.
// LDS = 51776 B -> 3 blocks/CU x 8 waves = 24 waves/CU capacity.
__launch_bounds__(512, 6)
__global__ void wave_main(float* __restrict__ out)
{
    __shared__ float S[12944];
    // S[0..4495]      = pp: param mirror (same layout as g_P)
    // S[4496..10895]  = sh1[m][j][lane]: 25*4*64
    // S[10896..12943] = shp[w][j][lane]: 8*4*64
    float* const pp  = S;
    float* const sh1 = S + 4496;
    float* const shp = S + 10896;

    // stage params global -> LDS (one-time; coalesced; conflict-free)
    for (int i = threadIdx.x; i < 4496; i += 512) pp[i] = g_P[i];
    __syncthreads();

    const int l = threadIdx.x & 63;
    const int w = __builtin_amdgcn_readfirstlane(threadIdx.x >> 6);
    const int tb = blockIdx.x * 256;
    const float STEP = 999.0f / 199999.0f;

    const float tv0 = fmaf((float)(tb + l), STEP, 1.0f);
    const float tv1 = fmaf((float)(tb + l + 64), STEP, 1.0f);

    // ---- layer 1 (with inline layer-0 recompute): wave w owns m = 4w+k ----
    float acc1[4][4] = {};
    float sum0[4] = {0.f, 0.f, 0.f, 0.f};
    {
        v4f qN  = *(const v4f*)&pp[0];
        v4f wwN = *(const v4f*)&pp[80 + 4 * w];
        v4f phN = *(const v4f*)&pp[80 + 32 + 4 * w];
        v4f CN  = *(const v4f*)&pp[80 + 64 + 4 * w];
#pragma clang loop unroll_count(2)
        for (int n = 0; n < 20; ++n) {
            const v4f q = qN, ww4 = wwN, ph4 = phN, C4 = CN;
            // prefetch n+1 from LDS (overread at n=19 -> layer2 block; unused)
            qN  = *(const v4f*)&pp[4 * (n + 1)];
            const float* __restrict__ pn = &pp[80 + 96 * (n + 1) + 4 * w];
            wwN = *(const v4f*)&pn[0];
            phN = *(const v4f*)&pn[32];
            CN  = *(const v4f*)&pn[64];

            // s0[n] at j=0..3 (Chebyshev over j)
            float s00 = q[3] * sinp(fmaf(q[0], tv0, q[1]));
            float s01 = q[3] * sinp(fmaf(q[0], tv1, q[1]));
            float s02 = fmaf(q[2], s01, -s00);
            float s03 = fmaf(q[2], s02, -s01);
            sum0[0] += s00; sum0[1] += s01; sum0[2] += s02; sum0[3] += s03;
#pragma unroll
            for (int k = 0; k < 4; ++k) {
                float x0 = sinp(fmaf(ww4[k], tv0, ph4[k]));
                float x1 = sinp(fmaf(ww4[k], tv1, ph4[k]));
                float x2 = fmaf(C4[k], x1, -x0);
                float x3 = fmaf(C4[k], x2, -x1);
                acc1[k][0] = fmaf(x0, s00, acc1[k][0]);
                acc1[k][1] = fmaf(x1, s01, acc1[k][1]);
                acc1[k][2] = fmaf(x2, s02, acc1[k][2]);
                acc1[k][3] = fmaf(x3, s03, acc1[k][3]);
            }
        }
    }
#pragma unroll
    for (int k = 0; k < 4; ++k) {
        if (4 * w + k < 25) {          // wave-uniform guard
#pragma unroll
            for (int j = 0; j < 4; ++j)
                sh1[((4 * w + k) * 4 + j) * 64 + l] =
                    fmaf(0.5f, acc1[k][j], 0.5f * sum0[j]);
        }
    }
    __syncthreads();

    // ---- layer 2: wave w owns m = 4w+k; s2 stays in regs ----
    float acc2[4][4] = {};
    float sum1[4] = {0.f, 0.f, 0.f, 0.f};
    {
        float s1N0 = sh1[(0 * 4 + 0) * 64 + l];
        float s1N1 = sh1[(0 * 4 + 1) * 64 + l];
        float s1N2 = sh1[(0 * 4 + 2) * 64 + l];
        float s1N3 = sh1[(0 * 4 + 3) * 64 + l];
        v4f wwN = *(const v4f*)&pp[2000 + 4 * w];
        v4f phN = *(const v4f*)&pp[2000 + 32 + 4 * w];
        v4f CN  = *(const v4f*)&pp[2000 + 64 + 4 * w];
#pragma clang loop unroll_count(2)
        for (int n = 0; n < 25; ++n) {
            const float s10 = s1N0, s11 = s1N1, s12 = s1N2, s13 = s1N3;
            const v4f ww4 = wwN, ph4 = phN, C4 = CN;
            // prefetch n+1 (s1 overread at n=24 -> shp region, uninit, unused;
            // param overread -> layer3 block)
            s1N0 = sh1[((n + 1) * 4 + 0) * 64 + l];
            s1N1 = sh1[((n + 1) * 4 + 1) * 64 + l];
            s1N2 = sh1[((n + 1) * 4 + 2) * 64 + l];
            s1N3 = sh1[((n + 1) * 4 + 3) * 64 + l];
            const float* __restrict__ pn = &pp[2000 + 96 * (n + 1) + 4 * w];
            wwN = *(const v4f*)&pn[0];
            phN = *(const v4f*)&pn[32];
            CN  = *(const v4f*)&pn[64];

            sum1[0] += s10; sum1[1] += s11; sum1[2] += s12; sum1[3] += s13;
#pragma unroll
            for (int k = 0; k < 4; ++k) {
                float x0 = sinp(fmaf(ww4[k], tv0, ph4[k]));
                float x1 = sinp(fmaf(ww4[k], tv1, ph4[k]));
                float x2 = fmaf(C4[k], x1, -x0);
                float x3 = fmaf(C4[k], x2, -x1);
                acc2[k][0] = fmaf(x0, s10, acc2[k][0]);
                acc2[k][1] = fmaf(x1, s11, acc2[k][1]);
                acc2[k][2] = fmaf(x2, s12, acc2[k][2]);
                acc2[k][3] = fmaf(x3, s13, acc2[k][3]);
            }
        }
    }
    float s2r[4][4];
#pragma unroll
    for (int k = 0; k < 4; ++k)
#pragma unroll
        for (int j = 0; j < 4; ++j)
            s2r[k][j] = fmaf(0.5f, acc2[k][j], 0.5f * sum1[j]);

    // ---- layer 3: per-wave partial over its own m-slice (registers) ----
    float pw[4] = {0.f, 0.f, 0.f, 0.f};
    {
        const float* __restrict__ pb = &pp[4400 + 4 * w];
#pragma unroll
        for (int k = 0; k < 4; ++k) {
            if (4 * w + k < 30) {      // wave-uniform guard (skips pads)
                const float ww = pb[k], ph = pb[32 + k], C = pb[64 + k];
                float x0 = sinp(fmaf(ww, tv0, ph));
                float x1 = sinp(fmaf(ww, tv1, ph));
                float x2 = fmaf(C, x1, -x0);
                float x3 = fmaf(C, x2, -x1);
                pw[0] = fmaf(fmaf(0.5f, x0, 0.5f), s2r[k][0], pw[0]);
                pw[1] = fmaf(fmaf(0.5f, x1, 0.5f), s2r[k][1], pw[1]);
                pw[2] = fmaf(fmaf(0.5f, x2, 0.5f), s2r[k][2], pw[2]);
                pw[3] = fmaf(fmaf(0.5f, x3, 0.5f), s2r[k][3], pw[3]);
            }
        }
    }
#pragma unroll
    for (int j = 0; j < 4; ++j)
        shp[(w * 4 + j) * 64 + l] = pw[j];   // [w][j][lane]: conflict-free
    __syncthreads();

    // cross-wave reduce: wave w (w<4) handles j == w
    if (w < 4) {
        float r = 0.0f;
#pragma unroll
        for (int w2 = 0; w2 < 8; ++w2)
            r += shp[(w2 * 4 + w) * 64 + l];
        const int tt = tb + l + 64 * w;
        if (tt < T_TOTAL) out[tt] = r;
    }
}

extern "C" void kernel_launch(void* const* d_in, const int* in_sizes, int n_in,
                              void* d_out, int out_size, void* d_ws, size_t ws_size,
                              hipStream_t stream) {
    (void)in_sizes; (void)n_in; (void)d_ws; (void)ws_size; (void)out_size;
    const float* A0    = (const float*)d_in[1];
    const float* w0    = (const float*)d_in[2];
    const float* phi0  = (const float*)d_in[3];
    const float* wc0   = (const float*)d_in[4];
    const float* phic0 = (const float*)d_in[5];
    const float* w1    = (const float*)d_in[6];
    const float* phi1  = (const float*)d_in[7];
    const float* wc1   = (const float*)d_in[8];
    const float* phic1 = (const float*)d_in[9];
    const float* w2    = (const float*)d_in[10];
    const float* phi2  = (const float*)d_in[11];
    const float* wc2   = (const float*)d_in[12];
    const float* phic2 = (const float*)d_in[13];
    const float* w3    = (const float*)d_in[14];
    const float* phi3  = (const float*)d_in[15];
    const float* wc3   = (const float*)d_in[16];
    const float* phic3 = (const float*)d_in[17];

    float* out = (float*)d_out;

    hipLaunchKernelGGL(prep_kernel, dim3(6), dim3(256), 0, stream,
                       A0, w0, phi0, wc0, phic0,
                       w1, phi1, wc1, phic1,
                       w2, phi2, wc2, phic2,
                       w3, phi3, wc3, phic3);

    const int grid = (T_TOTAL + 255) / 256;   // 782
    hipLaunchKernelGGL(wave_main, dim3(grid), dim3(512), 0, stream, out);
}

// Round 10
// 52.167 us; speedup vs baseline: 1.0885x; 1.0885x over previous
//
#include <hip/hip_runtime.h>
#include <hip/hip_bf16.h>

#define T_TOTAL 200000

typedef float v4f __attribute__((ext_vector_type(4)));

// Parameter block layout (floats), phases in REVOLUTIONS, +0.25-shifted so
// sin(theta) = cos(2*pi*(fract(rev)-0.5)) (even poly, no sign fixup):
// [0..79]      layer0 quads per n<20 at 4n: {ww0', ph0'+0.25, C0=2cos(w*64d), A0}
// [80..1999]   layer1: per n<20, 96-float block at 80+96n:
//              [+m]=ww1'  [+32+m]=ph1'+0.25  [+64+m]=C1, m<32 (pads m>=25:
//              ww=0, ph=0.25 -> sin==0, C=2)
// [2000..4399] layer2: per n<25, 96-float block at 2000+96n (pads m>=30)
// [4400..4495] layer3: [+k]=ww3' [+32+k]=ph3'+0.25 [+64+k]=C3, k<32 (pads>=30)
__device__ float g_P[4496];

// sin(2*pi*rev) via even poly: cos(2*pi*h), h = fract(rev)-0.5. |err| ~= 4e-5.
__device__ __forceinline__ float sinp(float rev) {
    float g = __builtin_amdgcn_fractf(rev);
    float h = g - 0.5f;
    float u = h * h;
    float p = fmaf(45.621248f, u, -82.391040f);
    p = fmaf(p, u, 64.671616f);
    p = fmaf(p, u, -19.730960f);
    p = fmaf(p, u, 0.9999618f);
    return p;
}

__global__ void prep_kernel(
    const float* __restrict__ A0,
    const float* __restrict__ w0, const float* __restrict__ phi0,
    const float* __restrict__ wc0, const float* __restrict__ phic0,
    const float* __restrict__ w1, const float* __restrict__ phi1,
    const float* __restrict__ wc1, const float* __restrict__ phic1,
    const float* __restrict__ w2, const float* __restrict__ phi2,
    const float* __restrict__ wc2, const float* __restrict__ phic2,
    const float* __restrict__ w3, const float* __restrict__ phi3,
    const float* __restrict__ wc3, const float* __restrict__ phic3)
{
    const int tid = blockIdx.x * blockDim.x + threadIdx.x;
    const int stride = blockDim.x * gridDim.x;

    const double I2PI = 0.15915494309189535;
    const double D64  = 64.0 * 999.0 / 199999.0;   // tv-step between j's

    const double ws0 = fmax((double)wc0[0], 0.0), ps0 = fmax((double)phic0[0], 0.0);
    const double ws1 = fmax((double)wc1[0], 0.0), ps1 = fmax((double)phic1[0], 0.0);
    const double ws2 = fmax((double)wc2[0], 0.0), ps2 = fmax((double)phic2[0], 0.0);
    const double ws3 = fmax((double)wc3[0], 0.0), ps3 = fmax((double)phic3[0], 0.0);

    for (int n = tid; n < 20; n += stride) {
        double wr = fmax((double)w0[n], 0.0) + ws0;
        g_P[4 * n]     = (float)(wr * I2PI);
        g_P[4 * n + 1] = (float)((fmax((double)phi0[n], 0.0) + ps0) * I2PI + 0.25);
        g_P[4 * n + 2] = (float)(2.0 * cos(wr * D64));
        g_P[4 * n + 3] = A0[n];
    }
    for (int k = tid; k < 20 * 32; k += stride) {
        const int n = k >> 5, m = k & 31;
        float wwf = 0.0f, phf = 0.25f, cf = 2.0f;
        if (m < 25) {
            const int s = m * 20 + n;
            double wr = fmax((double)w1[s], 0.0) + ws1;
            wwf = (float)(wr * I2PI);
            phf = (float)((fmax((double)phi1[s], 0.0) + ps1) * I2PI + 0.25);
            cf  = (float)(2.0 * cos(wr * D64));
        }
        g_P[80 + 96 * n + m]      = wwf;
        g_P[80 + 96 * n + 32 + m] = phf;
        g_P[80 + 96 * n + 64 + m] = cf;
    }
    for (int k = tid; k < 25 * 32; k += stride) {
        const int n = k >> 5, m = k & 31;
        float wwf = 0.0f, phf = 0.25f, cf = 2.0f;
        if (m < 30) {
            const int s = m * 25 + n;
            double wr = fmax((double)w2[s], 0.0) + ws2;
            wwf = (float)(wr * I2PI);
            phf = (float)((fmax((double)phi2[s], 0.0) + ps2) * I2PI + 0.25);
            cf  = (float)(2.0 * cos(wr * D64));
        }
        g_P[2000 + 96 * n + m]      = wwf;
        g_P[2000 + 96 * n + 32 + m] = phf;
        g_P[2000 + 96 * n + 64 + m] = cf;
    }
    for (int k = tid; k < 32; k += stride) {
        float wwf = 0.0f, phf = 0.25f, cf = 2.0f;
        if (k < 30) {
            double wr = fmax((double)w3[k], 0.0) + ws3;
            wwf = (float)(wr * I2PI);
            phf = (float)((fmax((double)phi3[k], 0.0) + ps3) * I2PI + 0.25);
            cf  = (float)(2.0 * cos(wr * D64));
        }
        g_P[4400 + k]      = wwf;
        g_P[4400 + 32 + k] = phf;
        g_P[4400 + 64 + k] = cf;
    }
}

// Block = 1024 threads = 16 WAVES covering 256 t-values: t = tb + l + 64j,
// j=0..3 per thread (R=4 Chebyshev: j=0,1 direct poly, j=2,3 one-fma
// recurrence x_{j+1} = C*x_j - x_{j-1}). Each wave owns only TWO m's per
// layer, with EXACT assignment (no pow-2 padding waste):
//   L0: wave w computes n=w (plus n=16+w for w<4) -> sh0
//   L1: waves 0..12 own m=2w,2w+1 (single pad m=25 discarded)
//   L2+L3 (fused): waves 0..14 own m=2w,2w+1 (exact 30)
// 16 waves/block doubles grid wave count vs R9 (12512 waves, the level that
// empirically gave 80% VALUBusy in R4). Waves idled by exact assignment
// barrier-wait; their SIMD slots are absorbed by the co-resident 2nd block:
// LDS 62464 B -> 2 blocks/CU; __launch_bounds__(1024,8) (=> 2 blocks/CU,
// VGPR capped at 64) keeps both resident.
// All t-staged LDS is scalar [row][j][lane]: strictly conflict-free.
__launch_bounds__(1024, 8)
__global__ void wave_main(float* __restrict__ out)
{
    __shared__ float S[15616];
    float* const sh0 = S;            // [20][4][64]
    float* const sh1 = S + 5120;     // [25][4][64]
    float* const shp = S + 11520;    // [16][4][64]

    const int l = threadIdx.x & 63;
    const int w = __builtin_amdgcn_readfirstlane(threadIdx.x >> 6);
    const int tb = blockIdx.x * 256;
    const float STEP = 999.0f / 199999.0f;

    const float tv0 = fmaf((float)(tb + l), STEP, 1.0f);
    const float tv1 = fmaf((float)(tb + l + 64), STEP, 1.0f);

    // ---- layer 0: wave w -> n=w (and n=16+w for w<4) ----
    {
        v4f q = *(const v4f*)&g_P[4 * w];
        float x0 = q[3] * sinp(fmaf(q[0], tv0, q[1]));
        float x1 = q[3] * sinp(fmaf(q[0], tv1, q[1]));
        float x2 = fmaf(q[2], x1, -x0);
        float x3 = fmaf(q[2], x2, -x1);
        sh0[w * 256 +       l] = x0;
        sh0[w * 256 +  64 + l] = x1;
        sh0[w * 256 + 128 + l] = x2;
        sh0[w * 256 + 192 + l] = x3;
        if (w < 4) {
            const int n = 16 + w;
            q = *(const v4f*)&g_P[4 * n];
            x0 = q[3] * sinp(fmaf(q[0], tv0, q[1]));
            x1 = q[3] * sinp(fmaf(q[0], tv1, q[1]));
            x2 = fmaf(q[2], x1, -x0);
            x3 = fmaf(q[2], x2, -x1);
            sh0[n * 256 +       l] = x0;
            sh0[n * 256 +  64 + l] = x1;
            sh0[n * 256 + 128 + l] = x2;
            sh0[n * 256 + 192 + l] = x3;
        }
    }
    __syncthreads();

    // ---- layer 1: waves 0..12, m = 2w, 2w+1 ----
    if (w < 13) {
        float acc[2][4] = {};
        float sum0[4] = {0.f, 0.f, 0.f, 0.f};
        const int m0 = 2 * w;
#pragma clang loop unroll_count(2)
        for (int n = 0; n < 20; ++n) {
            const float s00 = sh0[n * 256 +       l];
            const float s01 = sh0[n * 256 +  64 + l];
            const float s02 = sh0[n * 256 + 128 + l];
            const float s03 = sh0[n * 256 + 192 + l];
            sum0[0] += s00; sum0[1] += s01; sum0[2] += s02; sum0[3] += s03;
            const float* __restrict__ pb = &g_P[80 + 96 * n + m0];
            const float wwa = pb[0],  wwb = pb[1];
            const float pha = pb[32], phb = pb[33];
            const float Ca  = pb[64], Cb  = pb[65];
            {
                float x0 = sinp(fmaf(wwa, tv0, pha));
                float x1 = sinp(fmaf(wwa, tv1, pha));
                float x2 = fmaf(Ca, x1, -x0);
                float x3 = fmaf(Ca, x2, -x1);
                acc[0][0] = fmaf(x0, s00, acc[0][0]);
                acc[0][1] = fmaf(x1, s01, acc[0][1]);
                acc[0][2] = fmaf(x2, s02, acc[0][2]);
                acc[0][3] = fmaf(x3, s03, acc[0][3]);
            }
            {
                float x0 = sinp(fmaf(wwb, tv0, phb));
                float x1 = sinp(fmaf(wwb, tv1, phb));
                float x2 = fmaf(Cb, x1, -x0);
                float x3 = fmaf(Cb, x2, -x1);
                acc[1][0] = fmaf(x0, s00, acc[1][0]);
                acc[1][1] = fmaf(x1, s01, acc[1][1]);
                acc[1][2] = fmaf(x2, s02, acc[1][2]);
                acc[1][3] = fmaf(x3, s03, acc[1][3]);
            }
        }
#pragma unroll
        for (int j = 0; j < 4; ++j)
            sh1[m0 * 256 + j * 64 + l] = fmaf(0.5f, acc[0][j], 0.5f * sum0[j]);
        if (m0 + 1 < 25) {             // w=12: m=25 is the lone discard
#pragma unroll
            for (int j = 0; j < 4; ++j)
                sh1[(m0 + 1) * 256 + j * 64 + l] = fmaf(0.5f, acc[1][j], 0.5f * sum0[j]);
        }
    }
    __syncthreads();

    // ---- layer 2 + layer 3 (fused): waves 0..14, m = 2w, 2w+1 (exact 30) ----
    float pw[4] = {0.f, 0.f, 0.f, 0.f};
    if (w < 15) {
        float acc[2][4] = {};
        float sum1[4] = {0.f, 0.f, 0.f, 0.f};
        const int m0 = 2 * w;
#pragma clang loop unroll_count(2)
        for (int n = 0; n < 25; ++n) {
            const float s10 = sh1[n * 256 +       l];
            const float s11 = sh1[n * 256 +  64 + l];
            const float s12 = sh1[n * 256 + 128 + l];
            const float s13 = sh1[n * 256 + 192 + l];
            sum1[0] += s10; sum1[1] += s11; sum1[2] += s12; sum1[3] += s13;
            const float* __restrict__ pb = &g_P[2000 + 96 * n + m0];
            const float wwa = pb[0],  wwb = pb[1];
            const float pha = pb[32], phb = pb[33];
            const float Ca  = pb[64], Cb  = pb[65];
            {
                float x0 = sinp(fmaf(wwa, tv0, pha));
                float x1 = sinp(fmaf(wwa, tv1, pha));
                float x2 = fmaf(Ca, x1, -x0);
                float x3 = fmaf(Ca, x2, -x1);
                acc[0][0] = fmaf(x0, s10, acc[0][0]);
                acc[0][1] = fmaf(x1, s11, acc[0][1]);
                acc[0][2] = fmaf(x2, s12, acc[0][2]);
                acc[0][3] = fmaf(x3, s13, acc[0][3]);
            }
            {
                float x0 = sinp(fmaf(wwb, tv0, phb));
                float x1 = sinp(fmaf(wwb, tv1, phb));
                float x2 = fmaf(Cb, x1, -x0);
                float x3 = fmaf(Cb, x2, -x1);
                acc[1][0] = fmaf(x0, s10, acc[1][0]);
                acc[1][1] = fmaf(x1, s11, acc[1][1]);
                acc[1][2] = fmaf(x2, s12, acc[1][2]);
                acc[1][3] = fmaf(x3, s13, acc[1][3]);
            }
        }
        // layer 3 for this wave's two m's, s2 never leaves registers
        const float* __restrict__ p3 = &g_P[4400 + m0];
#pragma unroll
        for (int k = 0; k < 2; ++k) {
            const float ww = p3[k], ph = p3[32 + k], C = p3[64 + k];
            float x0 = sinp(fmaf(ww, tv0, ph));
            float x1 = sinp(fmaf(ww, tv1, ph));
            float x2 = fmaf(C, x1, -x0);
            float x3 = fmaf(C, x2, -x1);
            const float s20 = fmaf(0.5f, acc[k][0], 0.5f * sum1[0]);
            const float s21 = fmaf(0.5f, acc[k][1], 0.5f * sum1[1]);
            const float s22 = fmaf(0.5f, acc[k][2], 0.5f * sum1[2]);
            const float s23 = fmaf(0.5f, acc[k][3], 0.5f * sum1[3]);
            pw[0] = fmaf(fmaf(0.5f, x0, 0.5f), s20, pw[0]);
            pw[1] = fmaf(fmaf(0.5f, x1, 0.5f), s21, pw[1]);
            pw[2] = fmaf(fmaf(0.5f, x2, 0.5f), s22, pw[2]);
            pw[3] = fmaf(fmaf(0.5f, x3, 0.5f), s23, pw[3]);
        }
    }
#pragma unroll
    for (int j = 0; j < 4; ++j)
        shp[w * 256 + j * 64 + l] = pw[j];   // w=15 contributes zeros
    __syncthreads();

    // cross-wave reduce: wave w (w<4) handles j == w
    if (w < 4) {
        float r = 0.0f;
#pragma unroll
        for (int w2 = 0; w2 < 16; ++w2)
            r += shp[w2 * 256 + w * 64 + l];
        const int tt = tb + 64 * w + l;
        if (tt < T_TOTAL) out[tt] = r;
    }
}

extern "C" void kernel_launch(void* const* d_in, const int* in_sizes, int n_in,
                              void* d_out, int out_size, void* d_ws, size_t ws_size,
                              hipStream_t stream) {
    (void)in_sizes; (void)n_in; (void)d_ws; (void)ws_size; (void)out_size;
    const float* A0    = (const float*)d_in[1];
    const float* w0    = (const float*)d_in[2];
    const float* phi0  = (const float*)d_in[3];
    const float* wc0   = (const float*)d_in[4];
    const float* phic0 = (const float*)d_in[5];
    const float* w1    = (const float*)d_in[6];
    const float* phi1  = (const float*)d_in[7];
    const float* wc1   = (const float*)d_in[8];
    const float* phic1 = (const float*)d_in[9];
    const float* w2    = (const float*)d_in[10];
    const float* phi2  = (const float*)d_in[11];
    const float* wc2   = (const float*)d_in[12];
    const float* phic2 = (const float*)d_in[13];
    const float* w3    = (const float*)d_in[14];
    const float* phi3  = (const float*)d_in[15];
    const float* wc3   = (const float*)d_in[16];
    const float* phic3 = (const float*)d_in[17];

    float* out = (float*)d_out;

    hipLaunchKernelGGL(prep_kernel, dim3(6), dim3(256), 0, stream,
                       A0, w0, phi0, wc0, phic0,
                       w1, phi1, wc1, phic1,
                       w2, phi2, wc2, phic2,
                       w3, phi3, wc3, phic3);

    const int grid = (T_TOTAL + 255) / 256;   // 782
    hipLaunchKernelGGL(wave_main, dim3(grid), dim3(1024), 0, stream, out);
}

// Round 11
// 52.085 us; speedup vs baseline: 1.0902x; 1.0016x over previous
//
#include <hip/hip_runtime.h>
#include <hip/hip_bf16.h>

#define T_TOTAL 200000

typedef float v4f __attribute__((ext_vector_type(4)));

// Parameter block layout (floats), phases in REVOLUTIONS, +0.25-shifted so
// sin(theta) = cos(2*pi*(fract(rev)-0.5)) (even poly, no sign fixup):
// [0..79]      layer0 quads per n<20 at 4n: {ww0', ph0'+0.25, C0=2cos(w*64d), A0}
// [80..1999]   layer1: per n<20, 96-float block at 80+96n:
//              [+m]=ww1'  [+32+m]=ph1'+0.25  [+64+m]=C1, m<32 (pads m>=25)
// [2000..4399] layer2: per n<25, 96-float block at 2000+96n (pads m>=30)
// [4400..4495] layer3: [+k]=ww3' [+32+k]=ph3'+0.25 [+64+k]=C3, k<32 (pads>=30)
__device__ float g_P[4496];

// sin(2*pi*rev) via even poly: cos(2*pi*h), h = fract(rev)-0.5. |err| ~= 4e-5.
__device__ __forceinline__ float sinp(float rev) {
    float g = __builtin_amdgcn_fractf(rev);
    float h = g - 0.5f;
    float u = h * h;
    float p = fmaf(45.621248f, u, -82.391040f);
    p = fmaf(p, u, 64.671616f);
    p = fmaf(p, u, -19.730960f);
    p = fmaf(p, u, 0.9999618f);
    return p;
}

__global__ void prep_kernel(
    const float* __restrict__ A0,
    const float* __restrict__ w0, const float* __restrict__ phi0,
    const float* __restrict__ wc0, const float* __restrict__ phic0,
    const float* __restrict__ w1, const float* __restrict__ phi1,
    const float* __restrict__ wc1, const float* __restrict__ phic1,
    const float* __restrict__ w2, const float* __restrict__ phi2,
    const float* __restrict__ wc2, const float* __restrict__ phic2,
    const float* __restrict__ w3, const float* __restrict__ phi3,
    const float* __restrict__ wc3, const float* __restrict__ phic3)
{
    const int tid = blockIdx.x * blockDim.x + threadIdx.x;
    const int stride = blockDim.x * gridDim.x;

    const double I2PI = 0.15915494309189535;
    const double D64  = 64.0 * 999.0 / 199999.0;   // tv-step between j's

    const double ws0 = fmax((double)wc0[0], 0.0), ps0 = fmax((double)phic0[0], 0.0);
    const double ws1 = fmax((double)wc1[0], 0.0), ps1 = fmax((double)phic1[0], 0.0);
    const double ws2 = fmax((double)wc2[0], 0.0), ps2 = fmax((double)phic2[0], 0.0);
    const double ws3 = fmax((double)wc3[0], 0.0), ps3 = fmax((double)phic3[0], 0.0);

    for (int n = tid; n < 20; n += stride) {
        double wr = fmax((double)w0[n], 0.0) + ws0;
        g_P[4 * n]     = (float)(wr * I2PI);
        g_P[4 * n + 1] = (float)((fmax((double)phi0[n], 0.0) + ps0) * I2PI + 0.25);
        g_P[4 * n + 2] = (float)(2.0 * cos(wr * D64));
        g_P[4 * n + 3] = A0[n];
    }
    for (int k = tid; k < 20 * 32; k += stride) {
        const int n = k >> 5, m = k & 31;
        float wwf = 0.0f, phf = 0.25f, cf = 2.0f;
        if (m < 25) {
            const int s = m * 20 + n;
            double wr = fmax((double)w1[s], 0.0) + ws1;
            wwf = (float)(wr * I2PI);
            phf = (float)((fmax((double)phi1[s], 0.0) + ps1) * I2PI + 0.25);
            cf  = (float)(2.0 * cos(wr * D64));
        }
        g_P[80 + 96 * n + m]      = wwf;
        g_P[80 + 96 * n + 32 + m] = phf;
        g_P[80 + 96 * n + 64 + m] = cf;
    }
    for (int k = tid; k < 25 * 32; k += stride) {
        const int n = k >> 5, m = k & 31;
        float wwf = 0.0f, phf = 0.25f, cf = 2.0f;
        if (m < 30) {
            const int s = m * 25 + n;
            double wr = fmax((double)w2[s], 0.0) + ws2;
            wwf = (float)(wr * I2PI);
            phf = (float)((fmax((double)phi2[s], 0.0) + ps2) * I2PI + 0.25);
            cf  = (float)(2.0 * cos(wr * D64));
        }
        g_P[2000 + 96 * n + m]      = wwf;
        g_P[2000 + 96 * n + 32 + m] = phf;
        g_P[2000 + 96 * n + 64 + m] = cf;
    }
    for (int k = tid; k < 32; k += stride) {
        float wwf = 0.0f, phf = 0.25f, cf = 2.0f;
        if (k < 30) {
            double wr = fmax((double)w3[k], 0.0) + ws3;
            wwf = (float)(wr * I2PI);
            phf = (float)((fmax((double)phi3[k], 0.0) + ps3) * I2PI + 0.25);
            cf  = (float)(2.0 * cos(wr * D64));
        }
        g_P[4400 + k]      = wwf;
        g_P[4400 + 32 + k] = phf;
        g_P[4400 + 64 + k] = cf;
    }
}

// Block = 1024 threads = 16 waves covering 256 t-values: t = tb + l + 64j,
// j=0..3 per thread (R=4 Chebyshev: j=0,1 direct poly, j=2,3 one-fma
// recurrence). Exact m-assignment: L1 waves 0..12 own m=2w,2w+1 (one pad);
// L2+L3 fused, waves 0..14 own m=2w,2w+1 (exact 30).
// KEY vs R10: ALL hot-loop loads are DS (in-order lgkmcnt -> fine-grained
// waits). Params are staged to LDS in phases to fit under 64KB:
//   phase A: stage L1 params (pp1) + compute L0 -> sh0          (barrier)
//   L1 loop reads sh0 + pp1 (DS only) -> sh1                    (barrier)
//   phase C: stage L2+L3 params into the DEAD sh0 region (pp2)  (barrier)
//   L2+L3 loop reads sh1 + pp2 (DS only) -> pw in regs          (barrier)
//   shp aliases sh1; cross-wave reduce -> out
// LDS = 13440 floats = 53760 B; 16-wave blocks -> 2 blocks/CU (wave-capped).
__launch_bounds__(1024, 8)
__global__ void wave_main(float* __restrict__ out)
{
    __shared__ float S[13440];
    float* const pp1 = S;            // [20][96] L1 params        (1920)
    float* const sh0 = S + 1920;     // [20][4][64] s0            (5120)
    float* const sh1 = S + 7040;     // [25][4][64] s1            (6400)
    float* const pp2 = sh0;          // [26][96] L2+L3 params (2496, alias)
    float* const shp = sh1;          // [16][4][64] partials (4096, alias)

    const int l = threadIdx.x & 63;
    const int w = __builtin_amdgcn_readfirstlane(threadIdx.x >> 6);
    const int tb = blockIdx.x * 256;
    const float STEP = 999.0f / 199999.0f;

    const float tv0 = fmaf((float)(tb + l), STEP, 1.0f);
    const float tv1 = fmaf((float)(tb + l + 64), STEP, 1.0f);

    // ---- phase A: stage L1 params; layer 0 (params via one-time s_load) ----
    for (int i = threadIdx.x; i < 1920; i += 1024) pp1[i] = g_P[80 + i];
    {
        v4f q = *(const v4f*)&g_P[4 * w];
        float x0 = q[3] * sinp(fmaf(q[0], tv0, q[1]));
        float x1 = q[3] * sinp(fmaf(q[0], tv1, q[1]));
        float x2 = fmaf(q[2], x1, -x0);
        float x3 = fmaf(q[2], x2, -x1);
        sh0[w * 256 +       l] = x0;
        sh0[w * 256 +  64 + l] = x1;
        sh0[w * 256 + 128 + l] = x2;
        sh0[w * 256 + 192 + l] = x3;
        if (w < 4) {
            const int n = 16 + w;
            q = *(const v4f*)&g_P[4 * n];
            x0 = q[3] * sinp(fmaf(q[0], tv0, q[1]));
            x1 = q[3] * sinp(fmaf(q[0], tv1, q[1]));
            x2 = fmaf(q[2], x1, -x0);
            x3 = fmaf(q[2], x2, -x1);
            sh0[n * 256 +       l] = x0;
            sh0[n * 256 +  64 + l] = x1;
            sh0[n * 256 + 128 + l] = x2;
            sh0[n * 256 + 192 + l] = x3;
        }
    }
    __syncthreads();

    // ---- layer 1: waves 0..12, m = 2w, 2w+1 (all loads DS) ----
    if (w < 13) {
        float acc[2][4] = {};
        float sum0[4] = {0.f, 0.f, 0.f, 0.f};
        const int m0 = 2 * w;
#pragma clang loop unroll_count(4)
        for (int n = 0; n < 20; ++n) {
            const float s00 = sh0[n * 256 +       l];
            const float s01 = sh0[n * 256 +  64 + l];
            const float s02 = sh0[n * 256 + 128 + l];
            const float s03 = sh0[n * 256 + 192 + l];
            sum0[0] += s00; sum0[1] += s01; sum0[2] += s02; sum0[3] += s03;
            const float* __restrict__ pb = &pp1[96 * n + m0];
            const float wwa = pb[0],  wwb = pb[1];
            const float pha = pb[32], phb = pb[33];
            const float Ca  = pb[64], Cb  = pb[65];
            {
                float x0 = sinp(fmaf(wwa, tv0, pha));
                float x1 = sinp(fmaf(wwa, tv1, pha));
                float x2 = fmaf(Ca, x1, -x0);
                float x3 = fmaf(Ca, x2, -x1);
                acc[0][0] = fmaf(x0, s00, acc[0][0]);
                acc[0][1] = fmaf(x1, s01, acc[0][1]);
                acc[0][2] = fmaf(x2, s02, acc[0][2]);
                acc[0][3] = fmaf(x3, s03, acc[0][3]);
            }
            {
                float x0 = sinp(fmaf(wwb, tv0, phb));
                float x1 = sinp(fmaf(wwb, tv1, phb));
                float x2 = fmaf(Cb, x1, -x0);
                float x3 = fmaf(Cb, x2, -x1);
                acc[1][0] = fmaf(x0, s00, acc[1][0]);
                acc[1][1] = fmaf(x1, s01, acc[1][1]);
                acc[1][2] = fmaf(x2, s02, acc[1][2]);
                acc[1][3] = fmaf(x3, s03, acc[1][3]);
            }
        }
#pragma unroll
        for (int j = 0; j < 4; ++j)
            sh1[m0 * 256 + j * 64 + l] = fmaf(0.5f, acc[0][j], 0.5f * sum0[j]);
        if (m0 + 1 < 25) {             // w=12: m=25 is the lone discard
#pragma unroll
            for (int j = 0; j < 4; ++j)
                sh1[(m0 + 1) * 256 + j * 64 + l] = fmaf(0.5f, acc[1][j], 0.5f * sum0[j]);
        }
    }
    __syncthreads();

    // ---- phase C: stage L2+L3 params into dead sh0 region ----
    for (int i = threadIdx.x; i < 2496; i += 1024) pp2[i] = g_P[2000 + i];
    __syncthreads();

    // ---- layer 2 + 3 (fused): waves 0..14, m = 2w, 2w+1 (all loads DS) ----
    float pw[4] = {0.f, 0.f, 0.f, 0.f};
    if (w < 15) {
        float acc[2][4] = {};
        float sum1[4] = {0.f, 0.f, 0.f, 0.f};
        const int m0 = 2 * w;
#pragma clang loop unroll_count(4)
        for (int n = 0; n < 25; ++n) {
            const float s10 = sh1[n * 256 +       l];
            const float s11 = sh1[n * 256 +  64 + l];
            const float s12 = sh1[n * 256 + 128 + l];
            const float s13 = sh1[n * 256 + 192 + l];
            sum1[0] += s10; sum1[1] += s11; sum1[2] += s12; sum1[3] += s13;
            const float* __restrict__ pb = &pp2[96 * n + m0];
            const float wwa = pb[0],  wwb = pb[1];
            const float pha = pb[32], phb = pb[33];
            const float Ca  = pb[64], Cb  = pb[65];
            {
                float x0 = sinp(fmaf(wwa, tv0, pha));
                float x1 = sinp(fmaf(wwa, tv1, pha));
                float x2 = fmaf(Ca, x1, -x0);
                float x3 = fmaf(Ca, x2, -x1);
                acc[0][0] = fmaf(x0, s10, acc[0][0]);
                acc[0][1] = fmaf(x1, s11, acc[0][1]);
                acc[0][2] = fmaf(x2, s12, acc[0][2]);
                acc[0][3] = fmaf(x3, s13, acc[0][3]);
            }
            {
                float x0 = sinp(fmaf(wwb, tv0, phb));
                float x1 = sinp(fmaf(wwb, tv1, phb));
                float x2 = fmaf(Cb, x1, -x0);
                float x3 = fmaf(Cb, x2, -x1);
                acc[1][0] = fmaf(x0, s10, acc[1][0]);
                acc[1][1] = fmaf(x1, s11, acc[1][1]);
                acc[1][2] = fmaf(x2, s12, acc[1][2]);
                acc[1][3] = fmaf(x3, s13, acc[1][3]);
            }
        }
        // layer 3 for this wave's two m's; params at pp2[2400+..] (=g_P[4400+..])
        const float* __restrict__ p3 = &pp2[2400 + m0];
#pragma unroll
        for (int k = 0; k < 2; ++k) {
            const float ww = p3[k], ph = p3[32 + k], C = p3[64 + k];
            float x0 = sinp(fmaf(ww, tv0, ph));
            float x1 = sinp(fmaf(ww, tv1, ph));
            float x2 = fmaf(C, x1, -x0);
            float x3 = fmaf(C, x2, -x1);
            const float s20 = fmaf(0.5f, acc[k][0], 0.5f * sum1[0]);
            const float s21 = fmaf(0.5f, acc[k][1], 0.5f * sum1[1]);
            const float s22 = fmaf(0.5f, acc[k][2], 0.5f * sum1[2]);
            const float s23 = fmaf(0.5f, acc[k][3], 0.5f * sum1[3]);
            pw[0] = fmaf(fmaf(0.5f, x0, 0.5f), s20, pw[0]);
            pw[1] = fmaf(fmaf(0.5f, x1, 0.5f), s21, pw[1]);
            pw[2] = fmaf(fmaf(0.5f, x2, 0.5f), s22, pw[2]);
            pw[3] = fmaf(fmaf(0.5f, x3, 0.5f), s23, pw[3]);
        }
    }
    __syncthreads();                   // sh1 reads done; safe to alias as shp

#pragma unroll
    for (int j = 0; j < 4; ++j)
        shp[w * 256 + j * 64 + l] = pw[j];   // w=15 contributes zeros
    __syncthreads();

    // cross-wave reduce: wave w (w<4) handles j == w
    if (w < 4) {
        float r = 0.0f;
#pragma unroll
        for (int w2 = 0; w2 < 16; ++w2)
            r += shp[w2 * 256 + w * 64 + l];
        const int tt = tb + 64 * w + l;
        if (tt < T_TOTAL) out[tt] = r;
    }
}

extern "C" void kernel_launch(void* const* d_in, const int* in_sizes, int n_in,
                              void* d_out, int out_size, void* d_ws, size_t ws_size,
                              hipStream_t stream) {
    (void)in_sizes; (void)n_in; (void)d_ws; (void)ws_size; (void)out_size;
    const float* A0    = (const float*)d_in[1];
    const float* w0    = (const float*)d_in[2];
    const float* phi0  = (const float*)d_in[3];
    const float* wc0   = (const float*)d_in[4];
    const float* phic0 = (const float*)d_in[5];
    const float* w1    = (const float*)d_in[6];
    const float* phi1  = (const float*)d_in[7];
    const float* wc1   = (const float*)d_in[8];
    const float* phic1 = (const float*)d_in[9];
    const float* w2    = (const float*)d_in[10];
    const float* phi2  = (const float*)d_in[11];
    const float* wc2   = (const float*)d_in[12];
    const float* phic2 = (const float*)d_in[13];
    const float* w3    = (const float*)d_in[14];
    const float* phi3  = (const float*)d_in[15];
    const float* wc3   = (const float*)d_in[16];
    const float* phic3 = (const float*)d_in[17];

    float* out = (float*)d_out;

    hipLaunchKernelGGL(prep_kernel, dim3(6), dim3(256), 0, stream,
                       A0, w0, phi0, wc0, phic0,
                       w1, phi1, wc1, phic1,
                       w2, phi2, wc2, phic2,
                       w3, phi3, wc3, phic3);

    const int grid = (T_TOTAL + 255) / 256;   // 782
    hipLaunchKernelGGL(wave_main, dim3(grid), dim3(1024), 0, stream, out);
}